// Round 6
// baseline (660.417 us; speedup 1.0000x reference)
//
#include <hip/hip_runtime.h>
#include <hip/hip_bf16.h>
#include <math.h>

typedef __bf16 bf16;
typedef bf16 bf16x8 __attribute__((ext_vector_type(8)));
typedef bf16 bf16x4 __attribute__((ext_vector_type(4)));
typedef float f32x4 __attribute__((ext_vector_type(4)));

#define MFMA16(A,B,C) __builtin_amdgcn_mfma_f32_16x16x32_bf16(A,B,C,0,0,0)

static constexpr int QKV_ELEMS  = 768 * 256;
static constexpr int PROJ_ELEMS = 256 * 256;

// wave-local LDS ordering fence (stops compiler reordering; waits DS completion)
static __device__ __forceinline__ void lds_fence() {
    asm volatile("s_waitcnt lgkmcnt(0)" ::: "memory");
    __builtin_amdgcn_sched_barrier(0);
}

// explicit AGPR parking: keeps long-lived stash out of the arch-VGPR half
static __device__ __forceinline__ int to_agpr(unsigned v) {
    int a;
    asm volatile("v_accvgpr_write_b32 %0, %1" : "=a"(a) : "v"(v));
    return a;
}
static __device__ __forceinline__ unsigned from_agpr(int a) {
    unsigned v;
    asm volatile("v_accvgpr_read_b32 %0, %1" : "=v"(v) : "a"(a));
    return v;
}

// pack two f32 -> one u32 of 2 bf16 (low = a, high = b)
static __device__ __forceinline__ unsigned pack2(float a, float b) {
    bf16 xa = (bf16)a, xb = (bf16)b;
    unsigned short ua, ub;
    __builtin_memcpy(&ua, &xa, 2);
    __builtin_memcpy(&ub, &xb, 2);
    return (unsigned)ua | ((unsigned)ub << 16);
}

// Build an MFMA A/B fragment (bf16x8) from packed C-fragment registers.
// Dest lane (hi,lo) word w needs src lane 32*(hi&1)+16*(w>>1)+lo; register set
// LOW (PKL*) for dest lanes<32, HIGH (PKH*) for lanes>=32.
#define BUILD_FRAG(dst, PKL0, PKL1, PKH0, PKH1)                               \
  {                                                                            \
    int sA = ((lane & 16) << 1) + lo;                                          \
    int sB = sA + 16;                                                          \
    int a0 = __shfl((int)(PKL0), sA), a1 = __shfl((int)(PKL1), sA);            \
    int a2 = __shfl((int)(PKL0), sB), a3 = __shfl((int)(PKL1), sB);            \
    int b0 = __shfl((int)(PKH0), sA), b1 = __shfl((int)(PKH1), sA);            \
    int b2 = __shfl((int)(PKH0), sB), b3 = __shfl((int)(PKH1), sB);            \
    union { int w[4]; bf16x8 v; } u_;                                          \
    bool uh_ = (lane >= 32);                                                   \
    u_.w[0] = uh_ ? b0 : a0; u_.w[1] = uh_ ? b1 : a1;                          \
    u_.w[2] = uh_ ? b2 : a2; u_.w[3] = uh_ ? b3 : a3;                          \
    dst = u_.v;                                                                \
  }

// ---- K0: cast weights fp32 -> bf16 into ws ----
__global__ void cvt_weights(const float* __restrict__ qkv_w,
                            const float* __restrict__ proj_w,
                            bf16* __restrict__ wq, bf16* __restrict__ wp) {
    int i = blockIdx.x * 256 + threadIdx.x;
    if (i < QKV_ELEMS) wq[i] = (bf16)qkv_w[i];
    int j = i - QKV_ELEMS;
    if (j >= 0 && j < PROJ_ELEMS) wp[j] = (bf16)proj_w[j];
}

// ---- fused: shift + QKV + window attention + proj + unshift ----
// 256 threads = 4 waves; wave w owns heads 2w and 2w+1 (unrolled).
// One block per (batch, window). grid = 64*64.
__global__ __launch_bounds__(256, 3)
void swin_fused(const float* __restrict__ x,
                const bf16* __restrict__ wqkv,    // [768][256] bf16
                const bf16* __restrict__ wproj,   // [256][256] bf16
                const float* __restrict__ proj_b, // [256]
                const float* __restrict__ pose_g, // [15][15]
                float* __restrict__ out)
{
    // xbuf: x [64 tok][256 ch] bf16, chunk-swizzled; later overlaid with attn-out.
    __shared__ alignas(16) unsigned char xbuf[64 * 512];
    // per-wave vT [32 d][64 tok] bf16, swizzled (reused across the 2 heads)
    __shared__ alignas(16) unsigned char vbufs[4][4096];
    __shared__ float pose[225];

    const int tid  = threadIdx.x;
    const int wave = tid >> 6, lane = tid & 63;
    const int hi   = lane >> 4, lo = lane & 15;
    const int b    = blockIdx.x >> 6;
    const int w    = blockIdx.x & 63;
    const int wh   = w >> 3, wwi = w & 7;
    const bool mlow = (wh == 7), mright = (wwi == 7);
    const f32x4 zero4 = {0.f, 0.f, 0.f, 0.f};

    if (tid < 225) pose[tid] = pose_g[tid];

    // ---- phase 0: x (cyclic shift -4,-4) -> LDS bf16, swizzled, dense loads ----
    {
        int tok = tid >> 2, j = tid & 3;
        int gy = ((wh << 3) + (tok >> 3) + 4) & 63;
        int gx = ((wwi << 3) + (tok & 7) + 4) & 63;
        const float* src = x + (((b << 6) + gy) * 64 + gx) * 256;
        #pragma unroll
        for (int f = 0; f < 16; ++f) {
            int c4 = f * 4 + j;                       // float4 index within row
            float4 v = *(const float4*)(src + c4 * 4);
            bf16x4 bv;
            bv[0] = (bf16)v.x; bv[1] = (bf16)v.y; bv[2] = (bf16)v.z; bv[3] = (bf16)v.w;
            int chunk = (c4 >> 1) ^ (tok & 7);
            *(bf16x4*)(xbuf + tok * 512 + (chunk << 4) + ((c4 & 1) << 3)) = bv;
        }
    }
    __syncthreads();

    unsigned char* vb = vbufs[wave];
    int oPk[2][2][4][2];            // AGPR-parked packed attn-out [hp][dMt][it][p]
    const bool colmask_ = mright && (((lo & 7) >= 4) != (hi & 1));

    #pragma unroll
    for (int hp = 0; hp < 2; ++hp) {
        const int h = 2 * wave + hp;

        // ===== QK-pass: [qk]^T = mfma(A = W rows (global), B = x rows (LDS)) =====
        // C[n][tok]: lane holds col tok = 16*Nt + lo, rows n = 16*Mt + 4*hi + r
        unsigned pkQ[2][4][2];
        bf16x8 kA[4];
        {
            f32x4 acc[4][4];
            #pragma unroll
            for (int Mt = 0; Mt < 4; ++Mt)
                #pragma unroll
                for (int Nt = 0; Nt < 4; ++Nt) acc[Mt][Nt] = zero4;
            #pragma unroll
            for (int kk = 0; kk < 8; ++kk) {
                bf16x8 af[4], bx[4];
                #pragma unroll
                for (int Mt = 0; Mt < 4; ++Mt) {
                    int wrow = (Mt >> 1) * 256 + h * 32 + ((Mt & 1) << 4) + lo;  // q | k
                    af[Mt] = *(const bf16x8*)(wqkv + wrow * 256 + kk * 32 + hi * 8);
                }
                #pragma unroll
                for (int Nt = 0; Nt < 4; ++Nt) {
                    int tok = Nt * 16 + lo;
                    bx[Nt] = *(const bf16x8*)(xbuf + tok * 512 + (((kk * 4 + hi) ^ (tok & 7)) << 4));
                }
                #pragma unroll
                for (int Mt = 0; Mt < 4; ++Mt)
                    #pragma unroll
                    for (int Nt = 0; Nt < 4; ++Nt)
                        acc[Mt][Nt] = MFMA16(af[Mt], bx[Nt], acc[Mt][Nt]);
            }
            // pack q; pack k and IMMEDIATELY build kA frags (pkK dies here)
            unsigned pkK[2][4][2];
            #pragma unroll
            for (int Mt = 0; Mt < 2; ++Mt)
                #pragma unroll
                for (int Nt = 0; Nt < 4; ++Nt)
                    #pragma unroll
                    for (int p = 0; p < 2; ++p) {
                        pkQ[Mt][Nt][p] = pack2(acc[Mt][Nt][2 * p],     acc[Mt][Nt][2 * p + 1]);
                        pkK[Mt][Nt][p] = pack2(acc[2 + Mt][Nt][2 * p], acc[2 + Mt][Nt][2 * p + 1]);
                    }
            #pragma unroll
            for (int jt = 0; jt < 4; ++jt)
                BUILD_FRAG(kA[jt], pkK[0][jt][0], pkK[0][jt][1], pkK[1][jt][0], pkK[1][jt][1]);
        }

        // ===== V-pass: v^T = mfma(W_v rows, x rows) -> vT in LDS =====
        {
            f32x4 accv[2][4];
            #pragma unroll
            for (int vm = 0; vm < 2; ++vm)
                #pragma unroll
                for (int Nt = 0; Nt < 4; ++Nt) accv[vm][Nt] = zero4;
            #pragma unroll
            for (int kk = 0; kk < 8; ++kk) {
                bf16x8 af[2], bx[4];
                #pragma unroll
                for (int vm = 0; vm < 2; ++vm) {
                    int wrow = 512 + h * 32 + (vm << 4) + lo;
                    af[vm] = *(const bf16x8*)(wqkv + wrow * 256 + kk * 32 + hi * 8);
                }
                #pragma unroll
                for (int Nt = 0; Nt < 4; ++Nt) {
                    int tok = Nt * 16 + lo;
                    bx[Nt] = *(const bf16x8*)(xbuf + tok * 512 + (((kk * 4 + hi) ^ (tok & 7)) << 4));
                }
                #pragma unroll
                for (int vm = 0; vm < 2; ++vm)
                    #pragma unroll
                    for (int Nt = 0; Nt < 4; ++Nt)
                        accv[vm][Nt] = MFMA16(af[vm], bx[Nt], accv[vm][Nt]);
            }
            // hp=1 scatter must not overtake hp=0's pending PV reads of vb
            lds_fence();
            // vT [d][tok] scalar scatter (wave-local)
            #pragma unroll
            for (int vm = 0; vm < 2; ++vm)
                #pragma unroll
                for (int Nt = 0; Nt < 4; ++Nt) {
                    int tok = Nt * 16 + lo;
                    #pragma unroll
                    for (int r = 0; r < 4; ++r) {
                        int d = (vm << 4) + 4 * hi + r;
                        *(bf16*)(vb + d * 128 + (((tok >> 3) ^ (d & 7)) << 4) + ((tok & 7) << 1)) =
                            (bf16)accv[vm][Nt][r];
                    }
                }
        }
        lds_fence();   // vT stores complete before PV reads below

        // ===== merged S + softmax + PV + fold, one 16-col tile (it) at a time =====
        #pragma unroll
        for (int it = 0; it < 4; ++it) {
            bf16x8 qB;
            BUILD_FRAG(qB, pkQ[0][it][0], pkQ[0][it][1], pkQ[1][it][0], pkQ[1][it][1]);
            f32x4 s4[4];
            #pragma unroll
            for (int jt = 0; jt < 4; ++jt) s4[jt] = MFMA16(kA[jt], qB, zero4);

            float mx = -INFINITY;
            #pragma unroll
            for (int jt = 0; jt < 4; ++jt) {
                bool tilemask = mlow && ((it >= 2) != (jt >= 2));
                #pragma unroll
                for (int r = 0; r < 4; ++r) {
                    int drow = 2 * jt + (hi >> 1) - 2 * it - (lo >> 3) + 7;
                    int dcol = 4 * (hi & 1) + r - (lo & 7) + 7;
                    float s = s4[jt][r] * 0.17677669529663687f + pose[drow * 15 + dcol];
                    if (tilemask | colmask_) s = -INFINITY;
                    s4[jt][r] = s;
                    mx = fmaxf(mx, s);
                }
            }
            mx = fmaxf(mx, __shfl_xor(mx, 16));
            mx = fmaxf(mx, __shfl_xor(mx, 32));
            float sum = 0.f;
            #pragma unroll
            for (int jt = 0; jt < 4; ++jt)
                #pragma unroll
                for (int r = 0; r < 4; ++r) {
                    float e = __expf(s4[jt][r] - mx);
                    s4[jt][r] = e; sum += e;
                }
            sum += __shfl_xor(sum, 16);
            sum += __shfl_xor(sum, 32);
            float riv = 1.0f / sum;

            // pack this column-tile's P and consume it immediately
            unsigned pk[4][2];
            #pragma unroll
            for (int jt = 0; jt < 4; ++jt)
                #pragma unroll
                for (int p = 0; p < 2; ++p)
                    pk[jt][p] = pack2(s4[jt][2 * p], s4[jt][2 * p + 1]);
            f32x4 o2[2] = {zero4, zero4};
            #pragma unroll
            for (int ks = 0; ks < 2; ++ks) {
                bf16x8 pB;
                BUILD_FRAG(pB, pk[2 * ks][0], pk[2 * ks][1], pk[2 * ks + 1][0], pk[2 * ks + 1][1]);
                #pragma unroll
                for (int dMt = 0; dMt < 2; ++dMt) {
                    int d = dMt * 16 + lo;
                    bf16x8 va = *(const bf16x8*)(vb + d * 128 + (((ks * 4 + hi) ^ (d & 7)) << 4));
                    o2[dMt] = MFMA16(va, pB, o2[dMt]);
                }
            }
            // fold 1/sum, pack, park in AGPRs (static indices: hp/it unrolled)
            #pragma unroll
            for (int dMt = 0; dMt < 2; ++dMt) {
                oPk[hp][dMt][it][0] = to_agpr(pack2(o2[dMt][0] * riv, o2[dMt][1] * riv));
                oPk[hp][dMt][it][1] = to_agpr(pack2(o2[dMt][2] * riv, o2[dMt][3] * riv));
            }
        }
    }

    // ---- all waves done reading x -> overlay attn-out into xbuf ----
    __syncthreads();
    #pragma unroll
    for (int hp = 0; hp < 2; ++hp) {
        int h = 2 * wave + hp;
        #pragma unroll
        for (int dMt = 0; dMt < 2; ++dMt)
            #pragma unroll
            for (int it = 0; it < 4; ++it) {
                int tok = it * 16 + lo;
                union { unsigned u[2]; bf16x4 v; } uv;
                uv.u[0] = from_agpr(oPk[hp][dMt][it][0]);
                uv.u[1] = from_agpr(oPk[hp][dMt][it][1]);
                int chunk = ((h << 2) + (dMt << 1) + (hi >> 1)) ^ (tok & 7);
                *(bf16x4*)(xbuf + tok * 512 + (chunk << 4) + ((hi & 1) << 3)) = uv.v;
            }
    }
    __syncthreads();

    // ===== proj: out = ao * Wp^T + bias; wave w does out-ch 64w..64w+63 =====
    f32x4 pacc[4][4];
    #pragma unroll
    for (int Mt = 0; Mt < 4; ++Mt)
        #pragma unroll
        for (int nt = 0; nt < 4; ++nt) pacc[Mt][nt] = zero4;
    #pragma unroll
    for (int kk = 0; kk < 8; ++kk) {
        bf16x8 aA[4], bB[4];
        #pragma unroll
        for (int Mt = 0; Mt < 4; ++Mt) {
            int tok = Mt * 16 + lo;
            aA[Mt] = *(const bf16x8*)(xbuf + tok * 512 + (((kk * 4 + hi) ^ (tok & 7)) << 4));
        }
        #pragma unroll
        for (int nt = 0; nt < 4; ++nt) {
            int c = wave * 64 + nt * 16 + lo;
            bB[nt] = *(const bf16x8*)(wproj + c * 256 + kk * 32 + hi * 8);
        }
        #pragma unroll
        for (int Mt = 0; Mt < 4; ++Mt)
            #pragma unroll
            for (int nt = 0; nt < 4; ++nt)
                pacc[Mt][nt] = MFMA16(aA[Mt], bB[nt], pacc[Mt][nt]);
    }
    #pragma unroll
    for (int nt = 0; nt < 4; ++nt) {
        int c = wave * 64 + nt * 16 + lo;
        float pb2 = proj_b[c];
        #pragma unroll
        for (int Mt = 0; Mt < 4; ++Mt)
            #pragma unroll
            for (int r = 0; r < 4; ++r) {
                int tok = Mt * 16 + 4 * hi + r;
                int fy = ((wh << 3) + (tok >> 3) + 4) & 63;
                int fx = ((wwi << 3) + (tok & 7) + 4) & 63;
                out[(((b << 6) + fy) * 64 + fx) * 256 + c] = pacc[Mt][nt][r] + pb2;
            }
    }
}

extern "C" void kernel_launch(void* const* d_in, const int* in_sizes, int n_in,
                              void* d_out, int out_size, void* d_ws, size_t ws_size,
                              hipStream_t stream) {
    const float* x       = (const float*)d_in[0];
    const float* qkv_w   = (const float*)d_in[1];
    const float* proj_w  = (const float*)d_in[2];
    const float* proj_b  = (const float*)d_in[3];
    const float* pos_emb = (const float*)d_in[4];

    bf16* wq = (bf16*)d_ws;               // 768*256 bf16
    bf16* wp = wq + QKV_ELEMS;            // 256*256 bf16

    cvt_weights<<<dim3((QKV_ELEMS + PROJ_ELEMS) / 256), dim3(256), 0, stream>>>(
        qkv_w, proj_w, wq, wp);
    swin_fused<<<dim3(64 * 64), dim3(256), 0, stream>>>(
        x, wq, wp, proj_b, pos_emb, (float*)d_out);
}

// Round 7
// 566.019 us; speedup vs baseline: 1.1668x; 1.1668x over previous
//
#include <hip/hip_runtime.h>
#include <hip/hip_bf16.h>
#include <math.h>

typedef __bf16 bf16;
typedef bf16 bf16x8 __attribute__((ext_vector_type(8)));
typedef bf16 bf16x4 __attribute__((ext_vector_type(4)));
typedef float f32x4 __attribute__((ext_vector_type(4)));

#define MFMA16(A,B,C) __builtin_amdgcn_mfma_f32_16x16x32_bf16(A,B,C,0,0,0)

static constexpr int QKV_ELEMS  = 768 * 256;
static constexpr int PROJ_ELEMS = 256 * 256;
// per (b,w): 8 heads x {q[64][32], k[64][32], vT[32][64]} bf16 = 6144 elems/head
static constexpr size_t QKVWS_ELEMS = (size_t)4096 * 8 * 6144;

static __device__ __forceinline__ void lds_fence() {
    asm volatile("s_waitcnt lgkmcnt(0)" ::: "memory");
    __builtin_amdgcn_sched_barrier(0);
}

static __device__ __forceinline__ unsigned pack2(float a, float b) {
    bf16 xa = (bf16)a, xb = (bf16)b;
    unsigned short ua, ub;
    __builtin_memcpy(&ua, &xa, 2);
    __builtin_memcpy(&ub, &xb, 2);
    return (unsigned)ua | ((unsigned)ub << 16);
}

// Build an MFMA A/B fragment (bf16x8) from packed C-fragment registers.
#define BUILD_FRAG(dst, PKL0, PKL1, PKH0, PKH1)                               \
  {                                                                            \
    int sA = ((lane & 16) << 1) + lo;                                          \
    int sB = sA + 16;                                                          \
    int a0 = __shfl((int)(PKL0), sA), a1 = __shfl((int)(PKL1), sA);            \
    int a2 = __shfl((int)(PKL0), sB), a3 = __shfl((int)(PKL1), sB);            \
    int b0 = __shfl((int)(PKH0), sA), b1 = __shfl((int)(PKH1), sA);            \
    int b2 = __shfl((int)(PKH0), sB), b3 = __shfl((int)(PKH1), sB);            \
    union { int w[4]; bf16x8 v; } u_;                                          \
    bool uh_ = (lane >= 32);                                                   \
    u_.w[0] = uh_ ? b0 : a0; u_.w[1] = uh_ ? b1 : a1;                          \
    u_.w[2] = uh_ ? b2 : a2; u_.w[3] = uh_ ? b3 : a3;                          \
    dst = u_.v;                                                                \
  }

// ---- K0: cast weights fp32 -> bf16 into ws ----
__global__ void cvt_weights(const float* __restrict__ qkv_w,
                            const float* __restrict__ proj_w,
                            bf16* __restrict__ wq, bf16* __restrict__ wp) {
    int i = blockIdx.x * 256 + threadIdx.x;
    if (i < QKV_ELEMS) wq[i] = (bf16)qkv_w[i];
    int j = i - QKV_ELEMS;
    if (j >= 0 && j < PROJ_ELEMS) wp[j] = (bf16)proj_w[j];
}

// ======================= K1: shift + QKV GEMM -> ws =======================
// 256 thr = 4 waves; wave w computes heads 2w, 2w+1. One block per (b,window).
__global__ __launch_bounds__(256, 3)
void swin_qkv(const float* __restrict__ x,
              const bf16* __restrict__ wqkv,
              bf16* __restrict__ qkv_ws)
{
    __shared__ alignas(16) unsigned char xbuf[64 * 512];

    const int tid  = threadIdx.x;
    const int wave = tid >> 6, lane = tid & 63;
    const int hi   = lane >> 4, lo = lane & 15;
    const int b    = blockIdx.x >> 6;
    const int w    = blockIdx.x & 63;
    const int wh   = w >> 3, wwi = w & 7;
    const f32x4 zero4 = {0.f, 0.f, 0.f, 0.f};

    // x (cyclic shift -4,-4) -> LDS bf16, swizzled
    {
        int tok = tid >> 2, j = tid & 3;
        int gy = ((wh << 3) + (tok >> 3) + 4) & 63;
        int gx = ((wwi << 3) + (tok & 7) + 4) & 63;
        const float* src = x + (((b << 6) + gy) * 64 + gx) * 256;
        #pragma unroll
        for (int f = 0; f < 16; ++f) {
            int c4 = f * 4 + j;
            float4 v = *(const float4*)(src + c4 * 4);
            bf16x4 bv;
            bv[0] = (bf16)v.x; bv[1] = (bf16)v.y; bv[2] = (bf16)v.z; bv[3] = (bf16)v.w;
            int chunk = (c4 >> 1) ^ (tok & 7);
            *(bf16x4*)(xbuf + tok * 512 + (chunk << 4) + ((c4 & 1) << 3)) = bv;
        }
    }
    __syncthreads();

    #pragma unroll
    for (int hp = 0; hp < 2; ++hp) {
        const int h = 2 * wave + hp;
        bf16* base = qkv_ws + ((size_t)blockIdx.x * 8 + h) * 6144;

        // ---- QK pass: C[n][tok], n = 16*Mt + 4*hi + r, tok = 16*Nt + lo ----
        {
            f32x4 acc[4][4];
            #pragma unroll
            for (int Mt = 0; Mt < 4; ++Mt)
                #pragma unroll
                for (int Nt = 0; Nt < 4; ++Nt) acc[Mt][Nt] = zero4;
            #pragma unroll
            for (int kk = 0; kk < 8; ++kk) {
                bf16x8 af[4], bx[4];
                #pragma unroll
                for (int Mt = 0; Mt < 4; ++Mt) {
                    int wrow = (Mt >> 1) * 256 + h * 32 + ((Mt & 1) << 4) + lo;  // q | k
                    af[Mt] = *(const bf16x8*)(wqkv + wrow * 256 + kk * 32 + hi * 8);
                }
                #pragma unroll
                for (int Nt = 0; Nt < 4; ++Nt) {
                    int tok = Nt * 16 + lo;
                    bx[Nt] = *(const bf16x8*)(xbuf + tok * 512 + (((kk * 4 + hi) ^ (tok & 7)) << 4));
                }
                #pragma unroll
                for (int Mt = 0; Mt < 4; ++Mt)
                    #pragma unroll
                    for (int Nt = 0; Nt < 4; ++Nt)
                        acc[Mt][Nt] = MFMA16(af[Mt], bx[Nt], acc[Mt][Nt]);
            }
            // store q,k as [tok][32] (b64 vector stores: 4 consecutive d)
            #pragma unroll
            for (int Mt = 0; Mt < 4; ++Mt) {
                int sec = Mt >> 1;                          // 0=q, 1=k
                int d0  = ((Mt & 1) << 4) + 4 * hi;
                #pragma unroll
                for (int Nt = 0; Nt < 4; ++Nt) {
                    int tok = Nt * 16 + lo;
                    bf16x4 v;
                    #pragma unroll
                    for (int r = 0; r < 4; ++r) v[r] = (bf16)acc[Mt][Nt][r];
                    *(bf16x4*)(base + sec * 2048 + tok * 32 + d0) = v;
                }
            }
        }
        // ---- V pass -> vT [32][64] (scalar stores) ----
        {
            f32x4 accv[2][4];
            #pragma unroll
            for (int vm = 0; vm < 2; ++vm)
                #pragma unroll
                for (int Nt = 0; Nt < 4; ++Nt) accv[vm][Nt] = zero4;
            #pragma unroll
            for (int kk = 0; kk < 8; ++kk) {
                bf16x8 af[2], bx[4];
                #pragma unroll
                for (int vm = 0; vm < 2; ++vm) {
                    int wrow = 512 + h * 32 + (vm << 4) + lo;
                    af[vm] = *(const bf16x8*)(wqkv + wrow * 256 + kk * 32 + hi * 8);
                }
                #pragma unroll
                for (int Nt = 0; Nt < 4; ++Nt) {
                    int tok = Nt * 16 + lo;
                    bx[Nt] = *(const bf16x8*)(xbuf + tok * 512 + (((kk * 4 + hi) ^ (tok & 7)) << 4));
                }
                #pragma unroll
                for (int vm = 0; vm < 2; ++vm)
                    #pragma unroll
                    for (int Nt = 0; Nt < 4; ++Nt)
                        accv[vm][Nt] = MFMA16(af[vm], bx[Nt], accv[vm][Nt]);
            }
            #pragma unroll
            for (int vm = 0; vm < 2; ++vm)
                #pragma unroll
                for (int Nt = 0; Nt < 4; ++Nt) {
                    int tok = Nt * 16 + lo;
                    #pragma unroll
                    for (int r = 0; r < 4; ++r) {
                        int d = (vm << 4) + 4 * hi + r;
                        base[4096 + d * 64 + tok] = (bf16)accv[vm][Nt][r];
                    }
                }
        }
    }
}

// =================== K2: attention + proj + unshift ===================
// 256 thr = 4 waves; wave w does heads 2w,2w+1; q/k/v frags direct from ws.
__global__ __launch_bounds__(256, 3)
void swin_attn_proj(const bf16* __restrict__ qkv_ws,
                    const bf16* __restrict__ wproj,
                    const float* __restrict__ proj_b,
                    const float* __restrict__ pose_g,
                    float* __restrict__ out)
{
    __shared__ alignas(16) unsigned char xbuf[64 * 512];   // attn-out [64 tok][256 ch]
    __shared__ float pose[225];

    const int tid  = threadIdx.x;
    const int wave = tid >> 6, lane = tid & 63;
    const int hi   = lane >> 4, lo = lane & 15;
    const int b    = blockIdx.x >> 6;
    const int w    = blockIdx.x & 63;
    const int wh   = w >> 3, wwi = w & 7;
    const bool mlow = (wh == 7), mright = (wwi == 7);
    const f32x4 zero4 = {0.f, 0.f, 0.f, 0.f};

    if (tid < 225) pose[tid] = pose_g[tid];
    __syncthreads();

    const bool colmask_ = mright && (((lo & 7) >= 4) != (hi & 1));

    #pragma unroll
    for (int hp = 0; hp < 2; ++hp) {
        const int h = 2 * wave + hp;
        const bf16* base = qkv_ws + ((size_t)blockIdx.x * 8 + h) * 6144;

        // K fragments: rows j = 16*jt + lo, d-bytes 16*hi.. (contiguous 16B)
        bf16x8 kA[4];
        #pragma unroll
        for (int jt = 0; jt < 4; ++jt)
            kA[jt] = *(const bf16x8*)(base + 2048 + (16 * jt + lo) * 32 + hi * 8);

        #pragma unroll
        for (int it = 0; it < 4; ++it) {
            bf16x8 qB = *(const bf16x8*)(base + (16 * it + lo) * 32 + hi * 8);
            f32x4 s4[4];
            #pragma unroll
            for (int jt = 0; jt < 4; ++jt) s4[jt] = MFMA16(kA[jt], qB, zero4);

            float mx = -INFINITY;
            #pragma unroll
            for (int jt = 0; jt < 4; ++jt) {
                bool tilemask = mlow && ((it >= 2) != (jt >= 2));
                #pragma unroll
                for (int r = 0; r < 4; ++r) {
                    int drow = 2 * jt + (hi >> 1) - 2 * it - (lo >> 3) + 7;
                    int dcol = 4 * (hi & 1) + r - (lo & 7) + 7;
                    float s = s4[jt][r] * 0.17677669529663687f + pose[drow * 15 + dcol];
                    if (tilemask | colmask_) s = -INFINITY;
                    s4[jt][r] = s;
                    mx = fmaxf(mx, s);
                }
            }
            mx = fmaxf(mx, __shfl_xor(mx, 16));
            mx = fmaxf(mx, __shfl_xor(mx, 32));
            float sum = 0.f;
            #pragma unroll
            for (int jt = 0; jt < 4; ++jt)
                #pragma unroll
                for (int r = 0; r < 4; ++r) {
                    float e = __expf(s4[jt][r] - mx);
                    s4[jt][r] = e; sum += e;
                }
            sum += __shfl_xor(sum, 16);
            sum += __shfl_xor(sum, 32);
            float riv = 1.0f / sum;

            unsigned pk[4][2];
            #pragma unroll
            for (int jt = 0; jt < 4; ++jt)
                #pragma unroll
                for (int p = 0; p < 2; ++p)
                    pk[jt][p] = pack2(s4[jt][2 * p], s4[jt][2 * p + 1]);

            f32x4 o2[2] = {zero4, zero4};
            #pragma unroll
            for (int ks = 0; ks < 2; ++ks) {
                bf16x8 pB;
                BUILD_FRAG(pB, pk[2 * ks][0], pk[2 * ks][1], pk[2 * ks + 1][0], pk[2 * ks + 1][1]);
                #pragma unroll
                for (int dMt = 0; dMt < 2; ++dMt) {
                    // vT rows d = 16*dMt + lo, tok-bytes (32*ks + 8*hi)*2 (contig 16B)
                    bf16x8 va = *(const bf16x8*)(base + 4096 + (16 * dMt + lo) * 64 + ks * 32 + hi * 8);
                    o2[dMt] = MFMA16(va, pB, o2[dMt]);
                }
            }
            // fold 1/sum, write this head's slice of attn-out into LDS
            #pragma unroll
            for (int dMt = 0; dMt < 2; ++dMt) {
                int tok = it * 16 + lo;
                bf16x4 v;
                #pragma unroll
                for (int r = 0; r < 4; ++r) v[r] = (bf16)(o2[dMt][r] * riv);
                int chunk = ((h << 2) + (dMt << 1) + (hi >> 1)) ^ (tok & 7);
                *(bf16x4*)(xbuf + tok * 512 + (chunk << 4) + ((hi & 1) << 3)) = v;
            }
        }
    }
    __syncthreads();

    // ===== proj: out = ao * Wp^T + bias; wave w does out-ch 64w..64w+63 =====
    f32x4 pacc[4][4];
    #pragma unroll
    for (int Mt = 0; Mt < 4; ++Mt)
        #pragma unroll
        for (int nt = 0; nt < 4; ++nt) pacc[Mt][nt] = zero4;
    #pragma unroll
    for (int kk = 0; kk < 8; ++kk) {
        bf16x8 aA[4], bB[4];
        #pragma unroll
        for (int Mt = 0; Mt < 4; ++Mt) {
            int tok = Mt * 16 + lo;
            aA[Mt] = *(const bf16x8*)(xbuf + tok * 512 + (((kk * 4 + hi) ^ (tok & 7)) << 4));
        }
        #pragma unroll
        for (int nt = 0; nt < 4; ++nt) {
            int c = wave * 64 + nt * 16 + lo;
            bB[nt] = *(const bf16x8*)(wproj + c * 256 + kk * 32 + hi * 8);
        }
        #pragma unroll
        for (int Mt = 0; Mt < 4; ++Mt)
            #pragma unroll
            for (int nt = 0; nt < 4; ++nt)
                pacc[Mt][nt] = MFMA16(aA[Mt], bB[nt], pacc[Mt][nt]);
    }
    #pragma unroll
    for (int nt = 0; nt < 4; ++nt) {
        int c = wave * 64 + nt * 16 + lo;
        float pb2 = proj_b[c];
        #pragma unroll
        for (int Mt = 0; Mt < 4; ++Mt)
            #pragma unroll
            for (int r = 0; r < 4; ++r) {
                int tok = Mt * 16 + 4 * hi + r;
                int fy = ((wh << 3) + (tok >> 3) + 4) & 63;
                int fx = ((wwi << 3) + (tok & 7) + 4) & 63;
                out[(((b << 6) + fy) * 64 + fx) * 256 + c] = pacc[Mt][nt][r] + pb2;
            }
    }
}

// =================== fallback: R6 fused kernel at (256,2) ===================
__global__ __launch_bounds__(256, 2)
void swin_fused_fb(const float* __restrict__ x,
                   const bf16* __restrict__ wqkv,
                   const bf16* __restrict__ wproj,
                   const float* __restrict__ proj_b,
                   const float* __restrict__ pose_g,
                   float* __restrict__ out)
{
    __shared__ alignas(16) unsigned char xbuf[64 * 512];
    __shared__ alignas(16) unsigned char vbufs[4][4096];
    __shared__ float pose[225];

    const int tid  = threadIdx.x;
    const int wave = tid >> 6, lane = tid & 63;
    const int hi   = lane >> 4, lo = lane & 15;
    const int b    = blockIdx.x >> 6;
    const int w    = blockIdx.x & 63;
    const int wh   = w >> 3, wwi = w & 7;
    const bool mlow = (wh == 7), mright = (wwi == 7);
    const f32x4 zero4 = {0.f, 0.f, 0.f, 0.f};

    if (tid < 225) pose[tid] = pose_g[tid];
    {
        int tok = tid >> 2, j = tid & 3;
        int gy = ((wh << 3) + (tok >> 3) + 4) & 63;
        int gx = ((wwi << 3) + (tok & 7) + 4) & 63;
        const float* src = x + (((b << 6) + gy) * 64 + gx) * 256;
        #pragma unroll
        for (int f = 0; f < 16; ++f) {
            int c4 = f * 4 + j;
            float4 v = *(const float4*)(src + c4 * 4);
            bf16x4 bv;
            bv[0] = (bf16)v.x; bv[1] = (bf16)v.y; bv[2] = (bf16)v.z; bv[3] = (bf16)v.w;
            int chunk = (c4 >> 1) ^ (tok & 7);
            *(bf16x4*)(xbuf + tok * 512 + (chunk << 4) + ((c4 & 1) << 3)) = bv;
        }
    }
    __syncthreads();

    unsigned char* vb = vbufs[wave];
    unsigned pkO[2][2][4][2];
    const bool colmask_ = mright && (((lo & 7) >= 4) != (hi & 1));

    #pragma unroll
    for (int hp = 0; hp < 2; ++hp) {
        const int h = 2 * wave + hp;
        unsigned pkQ[2][4][2];
        bf16x8 kA[4];
        {
            f32x4 acc[4][4];
            #pragma unroll
            for (int Mt = 0; Mt < 4; ++Mt)
                #pragma unroll
                for (int Nt = 0; Nt < 4; ++Nt) acc[Mt][Nt] = zero4;
            #pragma unroll
            for (int kk = 0; kk < 8; ++kk) {
                bf16x8 af[4], bx[4];
                #pragma unroll
                for (int Mt = 0; Mt < 4; ++Mt) {
                    int wrow = (Mt >> 1) * 256 + h * 32 + ((Mt & 1) << 4) + lo;
                    af[Mt] = *(const bf16x8*)(wqkv + wrow * 256 + kk * 32 + hi * 8);
                }
                #pragma unroll
                for (int Nt = 0; Nt < 4; ++Nt) {
                    int tok = Nt * 16 + lo;
                    bx[Nt] = *(const bf16x8*)(xbuf + tok * 512 + (((kk * 4 + hi) ^ (tok & 7)) << 4));
                }
                #pragma unroll
                for (int Mt = 0; Mt < 4; ++Mt)
                    #pragma unroll
                    for (int Nt = 0; Nt < 4; ++Nt)
                        acc[Mt][Nt] = MFMA16(af[Mt], bx[Nt], acc[Mt][Nt]);
            }
            unsigned pkK[2][4][2];
            #pragma unroll
            for (int Mt = 0; Mt < 2; ++Mt)
                #pragma unroll
                for (int Nt = 0; Nt < 4; ++Nt)
                    #pragma unroll
                    for (int p = 0; p < 2; ++p) {
                        pkQ[Mt][Nt][p] = pack2(acc[Mt][Nt][2 * p],     acc[Mt][Nt][2 * p + 1]);
                        pkK[Mt][Nt][p] = pack2(acc[2 + Mt][Nt][2 * p], acc[2 + Mt][Nt][2 * p + 1]);
                    }
            #pragma unroll
            for (int jt = 0; jt < 4; ++jt)
                BUILD_FRAG(kA[jt], pkK[0][jt][0], pkK[0][jt][1], pkK[1][jt][0], pkK[1][jt][1]);
        }
        {
            f32x4 accv[2][4];
            #pragma unroll
            for (int vm = 0; vm < 2; ++vm)
                #pragma unroll
                for (int Nt = 0; Nt < 4; ++Nt) accv[vm][Nt] = zero4;
            #pragma unroll
            for (int kk = 0; kk < 8; ++kk) {
                bf16x8 af[2], bx[4];
                #pragma unroll
                for (int vm = 0; vm < 2; ++vm) {
                    int wrow = 512 + h * 32 + (vm << 4) + lo;
                    af[vm] = *(const bf16x8*)(wqkv + wrow * 256 + kk * 32 + hi * 8);
                }
                #pragma unroll
                for (int Nt = 0; Nt < 4; ++Nt) {
                    int tok = Nt * 16 + lo;
                    bx[Nt] = *(const bf16x8*)(xbuf + tok * 512 + (((kk * 4 + hi) ^ (tok & 7)) << 4));
                }
                #pragma unroll
                for (int vm = 0; vm < 2; ++vm)
                    #pragma unroll
                    for (int Nt = 0; Nt < 4; ++Nt)
                        accv[vm][Nt] = MFMA16(af[vm], bx[Nt], accv[vm][Nt]);
            }
            lds_fence();
            #pragma unroll
            for (int vm = 0; vm < 2; ++vm)
                #pragma unroll
                for (int Nt = 0; Nt < 4; ++Nt) {
                    int tok = Nt * 16 + lo;
                    #pragma unroll
                    for (int r = 0; r < 4; ++r) {
                        int d = (vm << 4) + 4 * hi + r;
                        *(bf16*)(vb + d * 128 + (((tok >> 3) ^ (d & 7)) << 4) + ((tok & 7) << 1)) =
                            (bf16)accv[vm][Nt][r];
                    }
                }
        }
        lds_fence();

        #pragma unroll
        for (int it = 0; it < 4; ++it) {
            bf16x8 qB;
            BUILD_FRAG(qB, pkQ[0][it][0], pkQ[0][it][1], pkQ[1][it][0], pkQ[1][it][1]);
            f32x4 s4[4];
            #pragma unroll
            for (int jt = 0; jt < 4; ++jt) s4[jt] = MFMA16(kA[jt], qB, zero4);
            float mx = -INFINITY;
            #pragma unroll
            for (int jt = 0; jt < 4; ++jt) {
                bool tilemask = mlow && ((it >= 2) != (jt >= 2));
                #pragma unroll
                for (int r = 0; r < 4; ++r) {
                    int drow = 2 * jt + (hi >> 1) - 2 * it - (lo >> 3) + 7;
                    int dcol = 4 * (hi & 1) + r - (lo & 7) + 7;
                    float s = s4[jt][r] * 0.17677669529663687f + pose[drow * 15 + dcol];
                    if (tilemask | colmask_) s = -INFINITY;
                    s4[jt][r] = s;
                    mx = fmaxf(mx, s);
                }
            }
            mx = fmaxf(mx, __shfl_xor(mx, 16));
            mx = fmaxf(mx, __shfl_xor(mx, 32));
            float sum = 0.f;
            #pragma unroll
            for (int jt = 0; jt < 4; ++jt)
                #pragma unroll
                for (int r = 0; r < 4; ++r) {
                    float e = __expf(s4[jt][r] - mx);
                    s4[jt][r] = e; sum += e;
                }
            sum += __shfl_xor(sum, 16);
            sum += __shfl_xor(sum, 32);
            float riv = 1.0f / sum;
            unsigned pk[4][2];
            #pragma unroll
            for (int jt = 0; jt < 4; ++jt)
                #pragma unroll
                for (int p = 0; p < 2; ++p)
                    pk[jt][p] = pack2(s4[jt][2 * p], s4[jt][2 * p + 1]);
            f32x4 o2[2] = {zero4, zero4};
            #pragma unroll
            for (int ks = 0; ks < 2; ++ks) {
                bf16x8 pB;
                BUILD_FRAG(pB, pk[2 * ks][0], pk[2 * ks][1], pk[2 * ks + 1][0], pk[2 * ks + 1][1]);
                #pragma unroll
                for (int dMt = 0; dMt < 2; ++dMt) {
                    int d = dMt * 16 + lo;
                    bf16x8 va = *(const bf16x8*)(vb + d * 128 + (((ks * 4 + hi) ^ (d & 7)) << 4));
                    o2[dMt] = MFMA16(va, pB, o2[dMt]);
                }
            }
            #pragma unroll
            for (int dMt = 0; dMt < 2; ++dMt) {
                pkO[hp][dMt][it][0] = pack2(o2[dMt][0] * riv, o2[dMt][1] * riv);
                pkO[hp][dMt][it][1] = pack2(o2[dMt][2] * riv, o2[dMt][3] * riv);
            }
        }
    }

    __syncthreads();
    #pragma unroll
    for (int hp = 0; hp < 2; ++hp) {
        int h = 2 * wave + hp;
        #pragma unroll
        for (int dMt = 0; dMt < 2; ++dMt)
            #pragma unroll
            for (int it = 0; it < 4; ++it) {
                int tok = it * 16 + lo;
                union { unsigned u[2]; bf16x4 v; } uv;
                uv.u[0] = pkO[hp][dMt][it][0];
                uv.u[1] = pkO[hp][dMt][it][1];
                int chunk = ((h << 2) + (dMt << 1) + (hi >> 1)) ^ (tok & 7);
                *(bf16x4*)(xbuf + tok * 512 + (chunk << 4) + ((hi & 1) << 3)) = uv.v;
            }
    }
    __syncthreads();

    f32x4 pacc[4][4];
    #pragma unroll
    for (int Mt = 0; Mt < 4; ++Mt)
        #pragma unroll
        for (int nt = 0; nt < 4; ++nt) pacc[Mt][nt] = zero4;
    #pragma unroll
    for (int kk = 0; kk < 8; ++kk) {
        bf16x8 aA[4], bB[4];
        #pragma unroll
        for (int Mt = 0; Mt < 4; ++Mt) {
            int tok = Mt * 16 + lo;
            aA[Mt] = *(const bf16x8*)(xbuf + tok * 512 + (((kk * 4 + hi) ^ (tok & 7)) << 4));
        }
        #pragma unroll
        for (int nt = 0; nt < 4; ++nt) {
            int c = wave * 64 + nt * 16 + lo;
            bB[nt] = *(const bf16x8*)(wproj + c * 256 + kk * 32 + hi * 8);
        }
        #pragma unroll
        for (int Mt = 0; Mt < 4; ++Mt)
            #pragma unroll
            for (int nt = 0; nt < 4; ++nt)
                pacc[Mt][nt] = MFMA16(aA[Mt], bB[nt], pacc[Mt][nt]);
    }
    #pragma unroll
    for (int nt = 0; nt < 4; ++nt) {
        int c = wave * 64 + nt * 16 + lo;
        float pb2 = proj_b[c];
        #pragma unroll
        for (int Mt = 0; Mt < 4; ++Mt)
            #pragma unroll
            for (int r = 0; r < 4; ++r) {
                int tok = Mt * 16 + 4 * hi + r;
                int fy = ((wh << 3) + (tok >> 3) + 4) & 63;
                int fx = ((wwi << 3) + (tok & 7) + 4) & 63;
                out[(((b << 6) + fy) * 64 + fx) * 256 + c] = pacc[Mt][nt][r] + pb2;
            }
    }
}

extern "C" void kernel_launch(void* const* d_in, const int* in_sizes, int n_in,
                              void* d_out, int out_size, void* d_ws, size_t ws_size,
                              hipStream_t stream) {
    const float* x       = (const float*)d_in[0];
    const float* qkv_w   = (const float*)d_in[1];
    const float* proj_w  = (const float*)d_in[2];
    const float* proj_b  = (const float*)d_in[3];
    const float* pos_emb = (const float*)d_in[4];

    bf16* wq = (bf16*)d_ws;               // 768*256 bf16
    bf16* wp = wq + QKV_ELEMS;            // 256*256 bf16
    bf16* qkv_ws = wp + PROJ_ELEMS;       // [4096][8][3][2048] bf16

    const size_t need = (size_t)(QKV_ELEMS + PROJ_ELEMS) * 2 + QKVWS_ELEMS * 2;

    cvt_weights<<<dim3((QKV_ELEMS + PROJ_ELEMS) / 256), dim3(256), 0, stream>>>(
        qkv_w, proj_w, wq, wp);

    if (ws_size >= need) {
        swin_qkv<<<dim3(64 * 64), dim3(256), 0, stream>>>(x, wq, qkv_ws);
        swin_attn_proj<<<dim3(64 * 64), dim3(256), 0, stream>>>(
            qkv_ws, wp, proj_b, pos_emb, (float*)d_out);
    } else {
        swin_fused_fb<<<dim3(64 * 64), dim3(256), 0, stream>>>(
            x, wq, wp, proj_b, pos_emb, (float*)d_out);
    }
}

// Round 8
// 489.485 us; speedup vs baseline: 1.3492x; 1.1564x over previous
//
#include <hip/hip_runtime.h>
#include <hip/hip_bf16.h>
#include <math.h>

typedef __bf16 bf16;
typedef bf16 bf16x8 __attribute__((ext_vector_type(8)));
typedef bf16 bf16x4 __attribute__((ext_vector_type(4)));
typedef float f32x4 __attribute__((ext_vector_type(4)));

#define MFMA16(A,B,C) __builtin_amdgcn_mfma_f32_16x16x32_bf16(A,B,C,0,0,0)

static constexpr int QKV_ELEMS  = 768 * 256;
static constexpr int PROJ_ELEMS = 256 * 256;
// per (b,w): 8 heads x {q[64][32], k[64][32], vT[32][64]} bf16 = 6144 elems/head
static constexpr size_t QKVWS_ELEMS = (size_t)4096 * 8 * 6144;

static __device__ __forceinline__ unsigned pack2(float a, float b) {
    bf16 xa = (bf16)a, xb = (bf16)b;
    unsigned short ua, ub;
    __builtin_memcpy(&ua, &xa, 2);
    __builtin_memcpy(&ub, &xb, 2);
    return (unsigned)ua | ((unsigned)ub << 16);
}

// Build an MFMA A/B fragment (bf16x8) from packed C-fragment registers.
#define BUILD_FRAG(dst, PKL0, PKL1, PKH0, PKH1)                               \
  {                                                                            \
    int sA = ((lane & 16) << 1) + lo;                                          \
    int sB = sA + 16;                                                          \
    int a0 = __shfl((int)(PKL0), sA), a1 = __shfl((int)(PKL1), sA);            \
    int a2 = __shfl((int)(PKL0), sB), a3 = __shfl((int)(PKL1), sB);            \
    int b0 = __shfl((int)(PKH0), sA), b1 = __shfl((int)(PKH1), sA);            \
    int b2 = __shfl((int)(PKH0), sB), b3 = __shfl((int)(PKH1), sB);            \
    union { int w[4]; bf16x8 v; } u_;                                          \
    bool uh_ = (lane >= 32);                                                   \
    u_.w[0] = uh_ ? b0 : a0; u_.w[1] = uh_ ? b1 : a1;                          \
    u_.w[2] = uh_ ? b2 : a2; u_.w[3] = uh_ ? b3 : a3;                          \
    dst = u_.v;                                                                \
  }

// ---- K0: cast weights fp32 -> bf16 into ws ----
__global__ void cvt_weights(const float* __restrict__ qkv_w,
                            const float* __restrict__ proj_w,
                            bf16* __restrict__ wq, bf16* __restrict__ wp) {
    int i = blockIdx.x * 256 + threadIdx.x;
    if (i < QKV_ELEMS) wq[i] = (bf16)qkv_w[i];
    int j = i - QKV_ELEMS;
    if (j >= 0 && j < PROJ_ELEMS) wp[j] = (bf16)proj_w[j];
}

// ======================= K1: shift + QKV GEMM -> ws =======================
// 256 thr = 4 waves; wave w owns heads 2w,2w+1 (64 contiguous weight rows per
// section). 3 passes (Q,K,V); all 32 weight frags of a pass batch-prefetched
// into registers before the MFMA stream (one latency wait per pass).
__global__ __launch_bounds__(256, 2)
void swin_qkv(const float* __restrict__ x,
              const bf16* __restrict__ wqkv,
              bf16* __restrict__ qkv_ws)
{
    __shared__ alignas(16) unsigned char xbuf[64 * 512];

    const int tid  = threadIdx.x;
    const int wave = tid >> 6, lane = tid & 63;
    const int hi   = lane >> 4, lo = lane & 15;
    const int b    = blockIdx.x >> 6;
    const int w    = blockIdx.x & 63;
    const int wh   = w >> 3, wwi = w & 7;
    const f32x4 zero4 = {0.f, 0.f, 0.f, 0.f};

    // x (cyclic shift -4,-4) -> LDS bf16, swizzled
    {
        int tok = tid >> 2, j = tid & 3;
        int gy = ((wh << 3) + (tok >> 3) + 4) & 63;
        int gx = ((wwi << 3) + (tok & 7) + 4) & 63;
        const float* src = x + (((b << 6) + gy) * 64 + gx) * 256;
        #pragma unroll
        for (int f = 0; f < 16; ++f) {
            int c4 = f * 4 + j;
            float4 v = *(const float4*)(src + c4 * 4);
            bf16x4 bv;
            bv[0] = (bf16)v.x; bv[1] = (bf16)v.y; bv[2] = (bf16)v.z; bv[3] = (bf16)v.w;
            int chunk = (c4 >> 1) ^ (tok & 7);
            *(bf16x4*)(xbuf + tok * 512 + (chunk << 4) + ((c4 & 1) << 3)) = bv;
        }
    }
    __syncthreads();

    bf16* base0 = qkv_ws + ((size_t)blockIdx.x * 8 + 2 * wave) * 6144;

    #pragma unroll
    for (int pass = 0; pass < 3; ++pass) {           // 0=Q, 1=K, 2=V
        const int secb = pass * 256 + 64 * wave;     // 64 contiguous weight rows

        // ---- batch-prefetch ALL weight fragments of this pass ----
        bf16x8 af[8][4];
        #pragma unroll
        for (int kk = 0; kk < 8; ++kk)
            #pragma unroll
            for (int Mt = 0; Mt < 4; ++Mt)
                af[kk][Mt] = *(const bf16x8*)(wqkv + (secb + 16 * Mt + lo) * 256 + kk * 32 + hi * 8);

        // ---- MFMA stream: C[n][tok], n = 16*Mt+4*hi+r, tok = 16*Nt+lo ----
        f32x4 acc[4][4];
        #pragma unroll
        for (int Mt = 0; Mt < 4; ++Mt)
            #pragma unroll
            for (int Nt = 0; Nt < 4; ++Nt) acc[Mt][Nt] = zero4;
        #pragma unroll
        for (int kk = 0; kk < 8; ++kk) {
            bf16x8 bx[4];
            #pragma unroll
            for (int Nt = 0; Nt < 4; ++Nt) {
                int tok = Nt * 16 + lo;
                bx[Nt] = *(const bf16x8*)(xbuf + tok * 512 + (((kk * 4 + hi) ^ (tok & 7)) << 4));
            }
            #pragma unroll
            for (int Mt = 0; Mt < 4; ++Mt)
                #pragma unroll
                for (int Nt = 0; Nt < 4; ++Nt)
                    acc[Mt][Nt] = MFMA16(af[kk][Mt], bx[Nt], acc[Mt][Nt]);
        }

        // ---- stores ----
        if (pass < 2) {
            // q/k as [tok][32] per head; head = 2w + (Mt>>1), d = 16*(Mt&1)+4*hi+r
            #pragma unroll
            for (int Mt = 0; Mt < 4; ++Mt) {
                bf16* hb = base0 + (Mt >> 1) * 6144 + pass * 2048;
                int d0 = ((Mt & 1) << 4) + 4 * hi;
                #pragma unroll
                for (int Nt = 0; Nt < 4; ++Nt) {
                    int tok = Nt * 16 + lo;
                    bf16x4 v;
                    #pragma unroll
                    for (int r = 0; r < 4; ++r) v[r] = (bf16)acc[Mt][Nt][r];
                    *(bf16x4*)(hb + tok * 32 + d0) = v;
                }
            }
        } else {
            // vT [32][64] per head (scalar stores)
            #pragma unroll
            for (int Mt = 0; Mt < 4; ++Mt) {
                bf16* hb = base0 + (Mt >> 1) * 6144 + 4096;
                #pragma unroll
                for (int Nt = 0; Nt < 4; ++Nt) {
                    int tok = Nt * 16 + lo;
                    #pragma unroll
                    for (int r = 0; r < 4; ++r) {
                        int d = ((Mt & 1) << 4) + 4 * hi + r;
                        hb[d * 64 + tok] = (bf16)acc[Mt][Nt][r];
                    }
                }
            }
        }
    }
}

// =================== K2: attention + proj + unshift ===================
// 256 thr = 4 waves; wave w does heads 2w,2w+1. All attention fragments of
// BOTH heads batch-prefetched (24 x 16B) before any compute; proj weights
// batched as bB[8][4].
__global__ __launch_bounds__(256, 2)
void swin_attn_proj(const bf16* __restrict__ qkv_ws,
                    const bf16* __restrict__ wproj,
                    const float* __restrict__ proj_b,
                    const float* __restrict__ pose_g,
                    float* __restrict__ out)
{
    __shared__ alignas(16) unsigned char xbuf[64 * 512];   // attn-out [64 tok][256 ch]
    __shared__ float pose[225];

    const int tid  = threadIdx.x;
    const int wave = tid >> 6, lane = tid & 63;
    const int hi   = lane >> 4, lo = lane & 15;
    const int b    = blockIdx.x >> 6;
    const int w    = blockIdx.x & 63;
    const int wh   = w >> 3, wwi = w & 7;
    const bool mlow = (wh == 7), mright = (wwi == 7);
    const f32x4 zero4 = {0.f, 0.f, 0.f, 0.f};

    if (tid < 225) pose[tid] = pose_g[tid];
    __syncthreads();

    const bool colmask_ = mright && (((lo & 7) >= 4) != (hi & 1));

    // ---- batch-prefetch all q/k/v fragments for both heads ----
    // fr[hp][0..3]=kA, [4..7]=qB, [8..11]=va (va[ks*2+dMt])
    bf16x8 fr[2][12];
    {
        const bf16* b0 = qkv_ws + ((size_t)blockIdx.x * 8 + 2 * wave) * 6144;
        #pragma unroll
        for (int hp = 0; hp < 2; ++hp) {
            const bf16* bb = b0 + hp * 6144;
            #pragma unroll
            for (int i = 0; i < 4; ++i) {
                fr[hp][i]     = *(const bf16x8*)(bb + 2048 + (16 * i + lo) * 32 + hi * 8);
                fr[hp][4 + i] = *(const bf16x8*)(bb + (16 * i + lo) * 32 + hi * 8);
                fr[hp][8 + i] = *(const bf16x8*)(bb + 4096 + (16 * (i & 1) + lo) * 64 + (i >> 1) * 32 + hi * 8);
            }
        }
    }

    #pragma unroll
    for (int hp = 0; hp < 2; ++hp) {
        const int h = 2 * wave + hp;

        #pragma unroll
        for (int it = 0; it < 4; ++it) {
            f32x4 s4[4];
            #pragma unroll
            for (int jt = 0; jt < 4; ++jt) s4[jt] = MFMA16(fr[hp][jt], fr[hp][4 + it], zero4);

            float mx = -INFINITY;
            #pragma unroll
            for (int jt = 0; jt < 4; ++jt) {
                bool tilemask = mlow && ((it >= 2) != (jt >= 2));
                #pragma unroll
                for (int r = 0; r < 4; ++r) {
                    int drow = 2 * jt + (hi >> 1) - 2 * it - (lo >> 3) + 7;
                    int dcol = 4 * (hi & 1) + r - (lo & 7) + 7;
                    float s = s4[jt][r] * 0.17677669529663687f + pose[drow * 15 + dcol];
                    if (tilemask | colmask_) s = -INFINITY;
                    s4[jt][r] = s;
                    mx = fmaxf(mx, s);
                }
            }
            mx = fmaxf(mx, __shfl_xor(mx, 16));
            mx = fmaxf(mx, __shfl_xor(mx, 32));
            float sum = 0.f;
            #pragma unroll
            for (int jt = 0; jt < 4; ++jt)
                #pragma unroll
                for (int r = 0; r < 4; ++r) {
                    float e = __expf(s4[jt][r] - mx);
                    s4[jt][r] = e; sum += e;
                }
            sum += __shfl_xor(sum, 16);
            sum += __shfl_xor(sum, 32);
            float riv = 1.0f / sum;

            unsigned pk[4][2];
            #pragma unroll
            for (int jt = 0; jt < 4; ++jt)
                #pragma unroll
                for (int p = 0; p < 2; ++p)
                    pk[jt][p] = pack2(s4[jt][2 * p], s4[jt][2 * p + 1]);

            f32x4 o2[2] = {zero4, zero4};
            #pragma unroll
            for (int ks = 0; ks < 2; ++ks) {
                bf16x8 pB;
                BUILD_FRAG(pB, pk[2 * ks][0], pk[2 * ks][1], pk[2 * ks + 1][0], pk[2 * ks + 1][1]);
                #pragma unroll
                for (int dMt = 0; dMt < 2; ++dMt)
                    o2[dMt] = MFMA16(fr[hp][8 + ks * 2 + dMt], pB, o2[dMt]);
            }
            // fold 1/sum, write this head's slice of attn-out into LDS
            #pragma unroll
            for (int dMt = 0; dMt < 2; ++dMt) {
                int tok = it * 16 + lo;
                bf16x4 v;
                #pragma unroll
                for (int r = 0; r < 4; ++r) v[r] = (bf16)(o2[dMt][r] * riv);
                int chunk = ((h << 2) + (dMt << 1) + (hi >> 1)) ^ (tok & 7);
                *(bf16x4*)(xbuf + tok * 512 + (chunk << 4) + ((hi & 1) << 3)) = v;
            }
        }
    }
    __syncthreads();

    // ===== proj: out = ao * Wp^T + bias; wave w does out-ch 64w..64w+63 =====
    // batch-prefetch all proj weight fragments
    bf16x8 bB[8][4];
    #pragma unroll
    for (int kk = 0; kk < 8; ++kk)
        #pragma unroll
        for (int nt = 0; nt < 4; ++nt) {
            int c = wave * 64 + nt * 16 + lo;
            bB[kk][nt] = *(const bf16x8*)(wproj + c * 256 + kk * 32 + hi * 8);
        }

    f32x4 pacc[4][4];
    #pragma unroll
    for (int Mt = 0; Mt < 4; ++Mt)
        #pragma unroll
        for (int nt = 0; nt < 4; ++nt) pacc[Mt][nt] = zero4;
    #pragma unroll
    for (int kk = 0; kk < 8; ++kk) {
        bf16x8 aA[4];
        #pragma unroll
        for (int Mt = 0; Mt < 4; ++Mt) {
            int tok = Mt * 16 + lo;
            aA[Mt] = *(const bf16x8*)(xbuf + tok * 512 + (((kk * 4 + hi) ^ (tok & 7)) << 4));
        }
        #pragma unroll
        for (int Mt = 0; Mt < 4; ++Mt)
            #pragma unroll
            for (int nt = 0; nt < 4; ++nt)
                pacc[Mt][nt] = MFMA16(aA[Mt], bB[kk][nt], pacc[Mt][nt]);
    }
    #pragma unroll
    for (int nt = 0; nt < 4; ++nt) {
        int c = wave * 64 + nt * 16 + lo;
        float pb2 = proj_b[c];
        #pragma unroll
        for (int Mt = 0; Mt < 4; ++Mt)
            #pragma unroll
            for (int r = 0; r < 4; ++r) {
                int tok = Mt * 16 + 4 * hi + r;
                int fy = ((wh << 3) + (tok >> 3) + 4) & 63;
                int fx = ((wwi << 3) + (tok & 7) + 4) & 63;
                out[(((b << 6) + fy) * 64 + fx) * 256 + c] = pacc[Mt][nt][r] + pb2;
            }
    }
}

extern "C" void kernel_launch(void* const* d_in, const int* in_sizes, int n_in,
                              void* d_out, int out_size, void* d_ws, size_t ws_size,
                              hipStream_t stream) {
    const float* x       = (const float*)d_in[0];
    const float* qkv_w   = (const float*)d_in[1];
    const float* proj_w  = (const float*)d_in[2];
    const float* proj_b  = (const float*)d_in[3];
    const float* pos_emb = (const float*)d_in[4];

    bf16* wq = (bf16*)d_ws;               // 768*256 bf16
    bf16* wp = wq + QKV_ELEMS;            // 256*256 bf16
    bf16* qkv_ws = wp + PROJ_ELEMS;       // [4096][8][3][2048] bf16

    cvt_weights<<<dim3((QKV_ELEMS + PROJ_ELEMS) / 256), dim3(256), 0, stream>>>(
        qkv_w, proj_w, wq, wp);
    swin_qkv<<<dim3(64 * 64), dim3(256), 0, stream>>>(x, wq, qkv_ws);
    swin_attn_proj<<<dim3(64 * 64), dim3(256), 0, stream>>>(
        qkv_ws, wp, proj_b, pos_emb, (float*)d_out);
}

// Round 9
// 446.528 us; speedup vs baseline: 1.4790x; 1.0962x over previous
//
#include <hip/hip_runtime.h>
#include <hip/hip_bf16.h>
#include <math.h>

typedef __bf16 bf16;
typedef bf16 bf16x8 __attribute__((ext_vector_type(8)));
typedef bf16 bf16x4 __attribute__((ext_vector_type(4)));
typedef float f32x4 __attribute__((ext_vector_type(4)));

#define MFMA16(A,B,C) __builtin_amdgcn_mfma_f32_16x16x32_bf16(A,B,C,0,0,0)

static constexpr int QKV_ELEMS  = 768 * 256;
static constexpr int PROJ_ELEMS = 256 * 256;
// per (b,w): 8 heads x {q[64][32], k[64][32], vT[32][64]} bf16 = 6144 elems/head
static constexpr size_t QKVWS_ELEMS = (size_t)4096 * 8 * 6144;

static __device__ __forceinline__ void lds_fence() {
    asm volatile("s_waitcnt lgkmcnt(0)" ::: "memory");
    __builtin_amdgcn_sched_barrier(0);
}

static __device__ __forceinline__ unsigned pack2(float a, float b) {
    bf16 xa = (bf16)a, xb = (bf16)b;
    unsigned short ua, ub;
    __builtin_memcpy(&ua, &xa, 2);
    __builtin_memcpy(&ub, &xb, 2);
    return (unsigned)ua | ((unsigned)ub << 16);
}

// Build an MFMA A/B fragment (bf16x8) from packed C-fragment registers.
#define BUILD_FRAG(dst, PKL0, PKL1, PKH0, PKH1)                               \
  {                                                                            \
    int sA = ((lane & 16) << 1) + lo;                                          \
    int sB = sA + 16;                                                          \
    int a0 = __shfl((int)(PKL0), sA), a1 = __shfl((int)(PKL1), sA);            \
    int a2 = __shfl((int)(PKL0), sB), a3 = __shfl((int)(PKL1), sB);            \
    int b0 = __shfl((int)(PKH0), sA), b1 = __shfl((int)(PKH1), sA);            \
    int b2 = __shfl((int)(PKH0), sB), b3 = __shfl((int)(PKH1), sB);            \
    union { int w[4]; bf16x8 v; } u_;                                          \
    bool uh_ = (lane >= 32);                                                   \
    u_.w[0] = uh_ ? b0 : a0; u_.w[1] = uh_ ? b1 : a1;                          \
    u_.w[2] = uh_ ? b2 : a2; u_.w[3] = uh_ ? b3 : a3;                          \
    dst = u_.v;                                                                \
  }

// ---- K0: cast weights fp32 -> bf16 into ws ----
__global__ void cvt_weights(const float* __restrict__ qkv_w,
                            const float* __restrict__ proj_w,
                            bf16* __restrict__ wq, bf16* __restrict__ wp) {
    int i = blockIdx.x * 256 + threadIdx.x;
    if (i < QKV_ELEMS) wq[i] = (bf16)qkv_w[i];
    int j = i - QKV_ELEMS;
    if (j >= 0 && j < PROJ_ELEMS) wp[j] = (bf16)proj_w[j];
}

// ======================= K1: shift + QKV GEMM -> ws =======================
// 256 thr = 4 waves; wave w owns heads 2w,2w+1. x staged fp32 via
// global_load_lds (source-swizzled, linear dest); B-frags = 2x ds_read_b128 +
// cvt_pk. vT stores vectorized through a per-wave LDS transpose buffer.
__global__ __launch_bounds__(256, 2)
void swin_qkv(const float* __restrict__ x,
              const bf16* __restrict__ wqkv,
              bf16* __restrict__ qkv_ws)
{
    __shared__ alignas(16) unsigned char xbuf[64 * 1024];   // [64 tok][256 ch] fp32, src-swizzled
    __shared__ alignas(16) unsigned char vtbuf[4][4096];    // per-wave vT staging

    const int tid  = threadIdx.x;
    const int wave = tid >> 6, lane = tid & 63;
    const int hi   = lane >> 4, lo = lane & 15;
    const int b    = blockIdx.x >> 6;
    const int w    = blockIdx.x & 63;
    const int wh   = w >> 3, wwi = w & 7;
    const f32x4 zero4 = {0.f, 0.f, 0.f, 0.f};

    // ---- phase 0: x (cyclic shift -4,-4) -> LDS fp32 via async DMA ----
    // stored chunk s of row tok = x chunk (s ^ (tok&7)); dest linear (lane*16).
    #pragma unroll
    for (int i = 0; i < 16; ++i) {
        int tok = wave * 16 + i;
        int gy = ((wh << 3) + (tok >> 3) + 4) & 63;
        int gx = ((wwi << 3) + (tok & 7) + 4) & 63;
        const float* srow = x + (((b << 6) + gy) * 64 + gx) * 256;
        const float* src  = srow + ((lane ^ (tok & 7)) << 2);   // 16B chunk per lane
        __builtin_amdgcn_global_load_lds(
            (const __attribute__((address_space(1))) unsigned int*)src,
            (__attribute__((address_space(3))) unsigned int*)(xbuf + tok * 1024),
            16, 0, 0);
    }
    asm volatile("s_waitcnt vmcnt(0)" ::: "memory");
    __syncthreads();

    // B-frag: x[tok][32kk+8hi .. +8] fp32 -> bf16x8 (k ascending)
    auto ldx = [&](int tok, int c16 /* = 8kk+2hi */) -> bf16x8 {
        const float4 a = *(const float4*)(xbuf + tok * 1024 + ((c16 ^ (tok & 7)) << 4));
        const float4 c = *(const float4*)(xbuf + tok * 1024 + (((c16 + 1) ^ (tok & 7)) << 4));
        union { unsigned u[4]; bf16x8 v; } r;
        r.u[0] = pack2(a.x, a.y); r.u[1] = pack2(a.z, a.w);
        r.u[2] = pack2(c.x, c.y); r.u[3] = pack2(c.z, c.w);
        return r.v;
    };

    bf16* base0 = qkv_ws + ((size_t)blockIdx.x * 8 + 2 * wave) * 6144;

    #pragma unroll
    for (int pass = 0; pass < 3; ++pass) {           // 0=Q, 1=K, 2=V
        const int secb = pass * 256 + 64 * wave;     // 64 contiguous weight rows

        // batch-prefetch all 32 weight fragments of this pass
        bf16x8 af[8][4];
        #pragma unroll
        for (int kk = 0; kk < 8; ++kk)
            #pragma unroll
            for (int Mt = 0; Mt < 4; ++Mt)
                af[kk][Mt] = *(const bf16x8*)(wqkv + (secb + 16 * Mt + lo) * 256 + kk * 32 + hi * 8);

        // MFMA stream: C[n][tok], n = 16*Mt+4*hi+r, tok = 16*Nt+lo
        f32x4 acc[4][4];
        #pragma unroll
        for (int Mt = 0; Mt < 4; ++Mt)
            #pragma unroll
            for (int Nt = 0; Nt < 4; ++Nt) acc[Mt][Nt] = zero4;
        #pragma unroll
        for (int kk = 0; kk < 8; ++kk) {
            bf16x8 bx[4];
            #pragma unroll
            for (int Nt = 0; Nt < 4; ++Nt)
                bx[Nt] = ldx(Nt * 16 + lo, 8 * kk + 2 * hi);
            #pragma unroll
            for (int Mt = 0; Mt < 4; ++Mt)
                #pragma unroll
                for (int Nt = 0; Nt < 4; ++Nt)
                    acc[Mt][Nt] = MFMA16(af[kk][Mt], bx[Nt], acc[Mt][Nt]);
        }

        if (pass < 2) {
            // q/k as [tok][32] per head; head = Mt>>1, d = 16*(Mt&1)+4*hi+r
            #pragma unroll
            for (int Mt = 0; Mt < 4; ++Mt) {
                bf16* hb = base0 + (Mt >> 1) * 6144 + pass * 2048;
                int d0 = ((Mt & 1) << 4) + 4 * hi;
                #pragma unroll
                for (int Nt = 0; Nt < 4; ++Nt) {
                    int tok = Nt * 16 + lo;
                    bf16x4 v;
                    #pragma unroll
                    for (int r = 0; r < 4; ++r) v[r] = (bf16)acc[Mt][Nt][r];
                    *(bf16x4*)(hb + tok * 32 + d0) = v;
                }
            }
        } else {
            // vT per head: scalar ds_writes (swizzled) -> b128 read-back -> b128 global
            unsigned char* vt = vtbuf[wave];
            #pragma unroll
            for (int hh = 0; hh < 2; ++hh) {
                #pragma unroll
                for (int m = 0; m < 2; ++m) {
                    int Mt = 2 * hh + m;
                    #pragma unroll
                    for (int Nt = 0; Nt < 4; ++Nt) {
                        int tok = Nt * 16 + lo;
                        #pragma unroll
                        for (int r = 0; r < 4; ++r) {
                            int d = (m << 4) + 4 * hi + r;         // (d>>2)&3 == hi
                            int byte = d * 128 + ((2 * tok) ^ (hi << 5));
                            *(bf16*)(vt + byte) = (bf16)acc[Mt][Nt][r];
                        }
                    }
                }
                lds_fence();   // writes visible before read-back
                bf16* hb = base0 + hh * 6144 + 4096;
                #pragma unroll
                for (int i = 0; i < 4; ++i) {
                    int d    = lane >> 1;
                    int tok0 = ((lane & 1) << 3) + (i << 4);
                    int byte = d * 128 + ((2 * tok0) ^ (((d >> 2) & 3) << 5));
                    bf16x8 vv = *(const bf16x8*)(vt + byte);
                    *(bf16x8*)(hb + d * 64 + tok0) = vv;
                }
                lds_fence();   // reads complete before next head overwrites vt
            }
        }
    }
}

// =================== K2: attention + proj + unshift ===================
// 256 thr = 4 waves; wave w does heads 2w,2w+1. All attention fragments of
// BOTH heads batch-prefetched (24 x 16B) before any compute; proj weights
// batched as bB[8][4].
__global__ __launch_bounds__(256, 2)
void swin_attn_proj(const bf16* __restrict__ qkv_ws,
                    const bf16* __restrict__ wproj,
                    const float* __restrict__ proj_b,
                    const float* __restrict__ pose_g,
                    float* __restrict__ out)
{
    __shared__ alignas(16) unsigned char xbuf[64 * 512];   // attn-out [64 tok][256 ch]
    __shared__ float pose[225];

    const int tid  = threadIdx.x;
    const int wave = tid >> 6, lane = tid & 63;
    const int hi   = lane >> 4, lo = lane & 15;
    const int b    = blockIdx.x >> 6;
    const int w    = blockIdx.x & 63;
    const int wh   = w >> 3, wwi = w & 7;
    const bool mlow = (wh == 7), mright = (wwi == 7);
    const f32x4 zero4 = {0.f, 0.f, 0.f, 0.f};

    if (tid < 225) pose[tid] = pose_g[tid];
    __syncthreads();

    const bool colmask_ = mright && (((lo & 7) >= 4) != (hi & 1));

    // fr[hp][0..3]=kA, [4..7]=qB, [8..11]=va (va[ks*2+dMt])
    bf16x8 fr[2][12];
    {
        const bf16* b0 = qkv_ws + ((size_t)blockIdx.x * 8 + 2 * wave) * 6144;
        #pragma unroll
        for (int hp = 0; hp < 2; ++hp) {
            const bf16* bb = b0 + hp * 6144;
            #pragma unroll
            for (int i = 0; i < 4; ++i) {
                fr[hp][i]     = *(const bf16x8*)(bb + 2048 + (16 * i + lo) * 32 + hi * 8);
                fr[hp][4 + i] = *(const bf16x8*)(bb + (16 * i + lo) * 32 + hi * 8);
                fr[hp][8 + i] = *(const bf16x8*)(bb + 4096 + (16 * (i & 1) + lo) * 64 + (i >> 1) * 32 + hi * 8);
            }
        }
    }

    #pragma unroll
    for (int hp = 0; hp < 2; ++hp) {
        const int h = 2 * wave + hp;

        #pragma unroll
        for (int it = 0; it < 4; ++it) {
            f32x4 s4[4];
            #pragma unroll
            for (int jt = 0; jt < 4; ++jt) s4[jt] = MFMA16(fr[hp][jt], fr[hp][4 + it], zero4);

            float mx = -INFINITY;
            #pragma unroll
            for (int jt = 0; jt < 4; ++jt) {
                bool tilemask = mlow && ((it >= 2) != (jt >= 2));
                #pragma unroll
                for (int r = 0; r < 4; ++r) {
                    int drow = 2 * jt + (hi >> 1) - 2 * it - (lo >> 3) + 7;
                    int dcol = 4 * (hi & 1) + r - (lo & 7) + 7;
                    float s = s4[jt][r] * 0.17677669529663687f + pose[drow * 15 + dcol];
                    if (tilemask | colmask_) s = -INFINITY;
                    s4[jt][r] = s;
                    mx = fmaxf(mx, s);
                }
            }
            mx = fmaxf(mx, __shfl_xor(mx, 16));
            mx = fmaxf(mx, __shfl_xor(mx, 32));
            float sum = 0.f;
            #pragma unroll
            for (int jt = 0; jt < 4; ++jt)
                #pragma unroll
                for (int r = 0; r < 4; ++r) {
                    float e = __expf(s4[jt][r] - mx);
                    s4[jt][r] = e; sum += e;
                }
            sum += __shfl_xor(sum, 16);
            sum += __shfl_xor(sum, 32);
            float riv = 1.0f / sum;

            unsigned pk[4][2];
            #pragma unroll
            for (int jt = 0; jt < 4; ++jt)
                #pragma unroll
                for (int p = 0; p < 2; ++p)
                    pk[jt][p] = pack2(s4[jt][2 * p], s4[jt][2 * p + 1]);

            f32x4 o2[2] = {zero4, zero4};
            #pragma unroll
            for (int ks = 0; ks < 2; ++ks) {
                bf16x8 pB;
                BUILD_FRAG(pB, pk[2 * ks][0], pk[2 * ks][1], pk[2 * ks + 1][0], pk[2 * ks + 1][1]);
                #pragma unroll
                for (int dMt = 0; dMt < 2; ++dMt)
                    o2[dMt] = MFMA16(fr[hp][8 + ks * 2 + dMt], pB, o2[dMt]);
            }
            #pragma unroll
            for (int dMt = 0; dMt < 2; ++dMt) {
                int tok = it * 16 + lo;
                bf16x4 v;
                #pragma unroll
                for (int r = 0; r < 4; ++r) v[r] = (bf16)(o2[dMt][r] * riv);
                int chunk = ((h << 2) + (dMt << 1) + (hi >> 1)) ^ (tok & 7);
                *(bf16x4*)(xbuf + tok * 512 + (chunk << 4) + ((hi & 1) << 3)) = v;
            }
        }
    }
    __syncthreads();

    // ===== proj: out = ao * Wp^T + bias; wave w does out-ch 64w..64w+63 =====
    bf16x8 bB[8][4];
    #pragma unroll
    for (int kk = 0; kk < 8; ++kk)
        #pragma unroll
        for (int nt = 0; nt < 4; ++nt) {
            int c = wave * 64 + nt * 16 + lo;
            bB[kk][nt] = *(const bf16x8*)(wproj + c * 256 + kk * 32 + hi * 8);
        }

    f32x4 pacc[4][4];
    #pragma unroll
    for (int Mt = 0; Mt < 4; ++Mt)
        #pragma unroll
        for (int nt = 0; nt < 4; ++nt) pacc[Mt][nt] = zero4;
    #pragma unroll
    for (int kk = 0; kk < 8; ++kk) {
        bf16x8 aA[4];
        #pragma unroll
        for (int Mt = 0; Mt < 4; ++Mt) {
            int tok = Mt * 16 + lo;
            aA[Mt] = *(const bf16x8*)(xbuf + tok * 512 + (((kk * 4 + hi) ^ (tok & 7)) << 4));
        }
        #pragma unroll
        for (int Mt = 0; Mt < 4; ++Mt)
            #pragma unroll
            for (int nt = 0; nt < 4; ++nt)
                pacc[Mt][nt] = MFMA16(aA[Mt], bB[kk][nt], pacc[Mt][nt]);
    }
    #pragma unroll
    for (int nt = 0; nt < 4; ++nt) {
        int c = wave * 64 + nt * 16 + lo;
        float pb2 = proj_b[c];
        #pragma unroll
        for (int Mt = 0; Mt < 4; ++Mt)
            #pragma unroll
            for (int r = 0; r < 4; ++r) {
                int tok = Mt * 16 + 4 * hi + r;
                int fy = ((wh << 3) + (tok >> 3) + 4) & 63;
                int fx = ((wwi << 3) + (tok & 7) + 4) & 63;
                out[(((b << 6) + fy) * 64 + fx) * 256 + c] = pacc[Mt][nt][r] + pb2;
            }
    }
}

extern "C" void kernel_launch(void* const* d_in, const int* in_sizes, int n_in,
                              void* d_out, int out_size, void* d_ws, size_t ws_size,
                              hipStream_t stream) {
    const float* x       = (const float*)d_in[0];
    const float* qkv_w   = (const float*)d_in[1];
    const float* proj_w  = (const float*)d_in[2];
    const float* proj_b  = (const float*)d_in[3];
    const float* pos_emb = (const float*)d_in[4];

    bf16* wq = (bf16*)d_ws;               // 768*256 bf16
    bf16* wp = wq + QKV_ELEMS;            // 256*256 bf16
    bf16* qkv_ws = wp + PROJ_ELEMS;       // [4096][8][3][2048] bf16

    cvt_weights<<<dim3((QKV_ELEMS + PROJ_ELEMS) / 256), dim3(256), 0, stream>>>(
        qkv_w, proj_w, wq, wp);
    swin_qkv<<<dim3(64 * 64), dim3(256), 0, stream>>>(x, wq, qkv_ws);
    swin_attn_proj<<<dim3(64 * 64), dim3(256), 0, stream>>>(
        qkv_ws, wp, proj_b, pos_emb, (float*)d_out);
}